// Round 1
// baseline (39.938 us; speedup 1.0000x reference)
//
#include <hip/hip_runtime.h>
#include <math.h>

#define BATCH 2
#define NDIRS 64
#define NCH   630
#define MPAD  640
#define HW    16384         // 128*128
#define KDIR  384           // 64 dirs * 6 moments
#define NT    12            // k-steps of 32
#define PANEL 64            // px per block
#define NPOSW 5             // m-positions (32 rows) per wave
#define NITER (NPOSW * NT)  // 60
#define BROWE 392           // Bs row stride in ushorts (784B)

// LDS layout (dynamic, 53760 B; A-tiles no longer staged in LDS)
#define BS_OFF 0            // 64 * 392 * 2       = 50176
#define TV_OFF 50176        // 640 * 4            =  2560
#define TG_OFF 52736        // 4 * 64 * 4         =  1024
#define LDS_TOTAL 53760

typedef float f32x4 __attribute__((ext_vector_type(4)));
typedef short s16x8 __attribute__((ext_vector_type(8)));

__device__ __forceinline__ ushort f2bf(float f) {
    unsigned u = __builtin_bit_cast(unsigned, f);
    u = (u + 0x7FFFu + ((u >> 16) & 1u)) >> 16;   // RNE
    return (ushort)u;
}

__device__ __forceinline__ uint cvt_pk_bf16(float lo, float hi) {
    uint r;
    asm("v_cvt_pk_bf16_f32 %0, %1, %2" : "=v"(r) : "v"(lo), "v"(hi));
    return r;
}

// nontemporal 16B load: TD stream has ZERO intra-kernel reuse -> do not
// allocate in L2 (protects L2-resident W2b from eviction).
__device__ __forceinline__ f32x4 ntload(const float* p) {
    return __builtin_nontemporal_load((const f32x4*)p);
}

// ---------------------------------------------------------------------------
// K1: fold per-channel Taylor coefficients into projection matrix (bf16),
// k-slot-swizzled: within each 32-k step, 8-k slot s = k8 ^ ((c>>1)&3).
// Rows 630..639 zero.
// ---------------------------------------------------------------------------
__global__ void prep_kernel(const float* __restrict__ t_vec,
                            const float* __restrict__ b_vec,
                            const float* __restrict__ P,
                            ushort* __restrict__ W2b) {
    int c = blockIdx.x;          // 0..639
    int j = threadIdx.x;         // 0..383  (true k index)
    float w = 0.0f;
    if (c < NCH) {
        int d = j / 6, k = j - d * 6;
        float t = t_vec[c];
        float bb = b_vec[c];
        float coeff;
        switch (k) {
            case 0:  coeff = -bb;                           break;
            case 1:  coeff = t * bb;                        break;
            case 2:  coeff = 0.5f * bb * bb;                break;
            case 3:  coeff = -0.5f * t * t * bb;            break;
            case 4:  coeff = -0.5f * t * bb * bb;           break;
            default: coeff = -(1.0f / 6.0f) * bb * bb * bb; break;
        }
        w = coeff * P[c * NDIRS + d];
    }
    int kstep = j >> 5, k5 = j & 31, k8 = k5 >> 3, klo = k5 & 7;
    int s = k8 ^ ((c >> 1) & 3);
    W2b[c * KDIR + kstep * 32 + s * 8 + klo] = f2bf(w);
}

// ---------------------------------------------------------------------------
// K2: panel-resident fused GEMM.
// 512 blocks (2/CU), 4 waves, barrier-free main loop. B panel staged once
// (depth-4 reg prefetch, swizzled+padded LDS). A fragments (W2b, L2-resident)
// are loaded DIRECTLY global->VGPR with a 2-iter triple-buffered register
// prefetch -- no LDS round-trip (removes 2 of 6 ds_read_b128/iter and all
// global_load_lds DMA writes from the loop's LDS pipe). Compiler's exact
// static vmcnt tracking reproduces the old counted waits (4 steady-state,
// 36 across EPI store bursts). Per-position EPIs, nontemporal output stores.
// ---------------------------------------------------------------------------
__global__ __launch_bounds__(256, 2) void fused_gemm(
        const ushort* __restrict__ W2b,   // [MPAD][KDIR] bf16, slot-swizzled
        const float*  __restrict__ TD,    // [B][KDIR][HW] f32 (theta_dir)
        const float*  __restrict__ t_vec, // [NCH]
        const float*  __restrict__ TG,    // [B][4][HW]
        float* __restrict__ out)          // [B][NCH][HW]
{
    extern __shared__ char lds[];

    const int nt_ = blockIdx.x;           // 0..255 (64-px panel)
    const int bz  = blockIdx.y;           // 0..1
    const int n0  = nt_ * PANEL;

    const int tid  = threadIdx.x;
    const int lane = tid & 63;
    const int wid  = tid >> 6;            // 0..3
    const int l15 = lane & 15, lhi = lane >> 4;
    const int aslot = lhi ^ ((l15 >> 1) & 3);

    ushort* bsU = (ushort*)(lds + BS_OFF);
    float*  tvl = (float*)(lds + TV_OFF);
    float*  tgl = (float*)(lds + TG_OFF);

    // ---- stage t_vec -> LDS (OOB-safe) ----
    tvl[tid]       = t_vec[tid];
    tvl[tid + 256] = t_vec[tid + 256];
    if (tid < NCH - 512) tvl[tid + 512] = t_vec[tid + 512];
    else if (tid + 512 < MPAD) tvl[tid + 512] = 0.0f;
    // ---- stage TG (4 planes x 64 px) ----
    {
        int p = tid >> 6, px = tid & 63;
        tgl[p * PANEL + px] = TG[((size_t)bz * 4 + p) * HW + n0 + px];
    }

    // ---- A fragment base + first two iterations' fragments ----
    // Lane reads row (wid*160 + pi*32 + m*16 + l15), stored slot aslot:
    // stored slot s holds true k8 = s ^ ((c>>1)&3); row base is a multiple
    // of 16 so (c>>1)&3 = (l15>>1)&3, giving true k8 = lhi. Identical math
    // to the old LDS-staged path, without the LDS round-trip.
    const ushort* aP = W2b + (wid * 160 + l15) * KDIR + aslot * 8;
    s16x8 afb[3][2];
    afb[0][0] = *(const s16x8*)(aP);                  // G=0: pi=0, ti=0
    afb[0][1] = *(const s16x8*)(aP + 16 * KDIR);
    afb[1][0] = *(const s16x8*)(aP + 32);             // G=1: pi=0, ti=1
    afb[1][1] = *(const s16x8*)(aP + 16 * KDIR + 32);
    __builtin_amdgcn_sched_barrier(0);

    // ---- stage B panel: 12 k-steps, depth-4 reg prefetch (NT loads) ----
    const int kq2 = tid >> 4;             // 0..15 -> krows {2kq2, 2kq2+1}
    const int pg  = tid & 15;             // px pg*4 .. pg*4+3
    const float* bR = TD + ((size_t)bz * KDIR + 2 * kq2) * HW + n0 + pg * 4;
    const int sxor = ((kq2 >> 2) ^ (pg & 3) ^ ((pg >> 2) & 3)) & 3;
    const int wbase = (kq2 & 3) * 2;      // uint pos within 8-ushort slot

    {
        f32x4 lo0, hi0, lo1, hi1, lo2, hi2, lo3, hi3;
        lo0 = ntload(bR);
        hi0 = ntload(bR + HW);
        lo1 = ntload(bR + (size_t)32 * HW);
        hi1 = ntload(bR + (size_t)33 * HW);
        lo2 = ntload(bR + (size_t)64 * HW);
        hi2 = ntload(bR + (size_t)65 * HW);

#define BSTEP(S, LC, HC, LN, HN)                                               \
        {                                                                      \
            if ((S) + 3 < NT) {                                                \
                LN = ntload(bR + (size_t)(((S) + 3) * 32) * HW);               \
                HN = ntload(bR + (size_t)(((S) + 3) * 32 + 1) * HW);           \
            }                                                                  \
            _Pragma("unroll")                                                  \
            for (int i = 0; i < 4; ++i) {                                      \
                uint w_ = cvt_pk_bf16(LC[i], HC[i]);                           \
                int s_ = (sxor ^ i) & 3;                                       \
                *(uint*)&bsU[(pg * 4 + i) * BROWE + (S) * 32 + s_ * 8 + wbase] = w_; \
            }                                                                  \
        }
        BSTEP(0, lo0, hi0, lo3, hi3)  BSTEP(1, lo1, hi1, lo0, hi0)
        BSTEP(2, lo2, hi2, lo1, hi1)  BSTEP(3, lo3, hi3, lo2, hi2)
        BSTEP(4, lo0, hi0, lo3, hi3)  BSTEP(5, lo1, hi1, lo0, hi0)
        BSTEP(6, lo2, hi2, lo1, hi1)  BSTEP(7, lo3, hi3, lo2, hi2)
        BSTEP(8, lo0, hi0, lo3, hi3)  BSTEP(9, lo1, hi1, lo0, hi0)
        BSTEP(10, lo2, hi2, lo1, hi1) BSTEP(11, lo3, hi3, lo2, hi2)
#undef BSTEP
    }

    // ---- single barrier: Bs/tv/tg visible ----
    asm volatile("s_waitcnt lgkmcnt(0)" ::: "memory");
    __builtin_amdgcn_s_barrier();
    __builtin_amdgcn_sched_barrier(0);

    // hoist TG values (wave covers all 64 px: px = n*16 + l15)
    float gg[4][4];
    #pragma unroll
    for (int n = 0; n < 4; ++n)
        #pragma unroll
        for (int p = 0; p < 4; ++p) gg[n][p] = tgl[p * PANEL + n * 16 + l15];

    f32x4 acc[2][4];
    #pragma unroll
    for (int m = 0; m < 2; ++m)
        #pragma unroll
        for (int n = 0; n < 4; ++n) acc[m][n] = (f32x4){0.f, 0.f, 0.f, 0.f};

    // ---- 60-iter pipeline; A prefetch 2 iters ahead into reg triple-buffer ----
#define ITER(G)                                                                \
    {                                                                          \
        constexpr int T_ = (G) % NT, buf_ = (G) % 3;                           \
        constexpr int gn_ = (G) + 2;                                           \
        if constexpr (gn_ < NITER) {                                           \
            constexpr int pi_ = gn_ / NT, ti_ = gn_ % NT, nb_ = gn_ % 3;       \
            afb[nb_][0] = *(const s16x8*)(aP + (pi_ * 32) * KDIR + ti_ * 32);  \
            afb[nb_][1] = *(const s16x8*)(aP + (pi_ * 32 + 16) * KDIR          \
                                          + ti_ * 32);                         \
            __builtin_amdgcn_sched_barrier(0);                                 \
        }                                                                      \
        s16x8 bf[4];                                                           \
        _Pragma("unroll")                                                      \
        for (int n = 0; n < 4; ++n) {                                          \
            const int rs_ = (lhi ^ (l15 & 3) ^ ((l15 >> 2) & 3) ^ (n)) & 3;    \
            bf[n] = *(const s16x8*)&bsU[(n * 16 + l15) * BROWE + T_ * 32 + rs_ * 8]; \
        }                                                                      \
        __builtin_amdgcn_s_setprio(1);                                         \
        _Pragma("unroll")                                                      \
        for (int m = 0; m < 2; ++m)                                            \
            _Pragma("unroll")                                                  \
            for (int n = 0; n < 4; ++n)                                        \
                acc[m][n] = __builtin_amdgcn_mfma_f32_16x16x32_bf16(           \
                                afb[buf_][m], bf[n], acc[m][n], 0, 0, 0);      \
        __builtin_amdgcn_s_setprio(0);                                         \
    }

// EPI for positions 0..3: c = wid*160 + P*32 + ... <= 3*160+127 = 607 < 630,
// so stores are UNCONDITIONAL -> exactly 32 per thread.
#define EPI(P_)                                                                \
    {                                                                          \
        _Pragma("unroll")                                                      \
        for (int m = 0; m < 2; ++m) {                                          \
            _Pragma("unroll")                                                  \
            for (int r = 0; r < 4; ++r) {                                      \
                int c = wid * 160 + (P_) * 32 + m * 16 + lhi * 4 + r;          \
                float t_ = tvl[c];                                             \
                float ct1 = -t_, ct2 = 0.5f * t_ * t_;                         \
                float ct3 = -(1.0f / 6.0f) * t_ * t_ * t_;                     \
                float* orow = out + ((size_t)bz * NCH + c) * HW + n0 + l15;    \
                _Pragma("unroll")                                              \
                for (int n = 0; n < 4; ++n) {                                  \
                    float base = gg[n][0] + ct1 * gg[n][1]                     \
                               + ct2 * gg[n][2] + ct3 * gg[n][3];              \
                    __builtin_nontemporal_store(                               \
                        __expf(acc[m][n][r] + base), orow + n * 16);           \
                }                                                              \
            }                                                                  \
        }                                                                      \
        _Pragma("unroll")                                                      \
        for (int m = 0; m < 2; ++m)                                            \
            _Pragma("unroll")                                                  \
            for (int n = 0; n < 4; ++n) acc[m][n] = (f32x4){0.f,0.f,0.f,0.f};  \
    }

    ITER(0)  ITER(1)  ITER(2)  ITER(3)  ITER(4)  ITER(5)
    ITER(6)  ITER(7)  ITER(8)  ITER(9)  ITER(10) ITER(11)
    EPI(0)
    ITER(12) ITER(13) ITER(14) ITER(15) ITER(16) ITER(17)
    ITER(18) ITER(19) ITER(20) ITER(21) ITER(22) ITER(23)
    EPI(1)
    ITER(24) ITER(25) ITER(26) ITER(27) ITER(28) ITER(29)
    ITER(30) ITER(31) ITER(32) ITER(33) ITER(34) ITER(35)
    EPI(2)
    ITER(36) ITER(37) ITER(38) ITER(39) ITER(40) ITER(41)
    ITER(42) ITER(43) ITER(44) ITER(45) ITER(46) ITER(47)
    EPI(3)
    ITER(48) ITER(49) ITER(50) ITER(51) ITER(52) ITER(53)
    ITER(54) ITER(55) ITER(56) ITER(57) ITER(58) ITER(59)

    // ---- terminal EPI (position 4: rows 608..639 region, guarded) ----
    {
        #pragma unroll
        for (int m = 0; m < 2; ++m) {
            #pragma unroll
            for (int r = 0; r < 4; ++r) {
                int c = wid * 160 + 4 * 32 + m * 16 + lhi * 4 + r;
                if (c < NCH) {
                    float t_ = tvl[c];
                    float ct1 = -t_, ct2 = 0.5f * t_ * t_;
                    float ct3 = -(1.0f / 6.0f) * t_ * t_ * t_;
                    float* orow = out + ((size_t)bz * NCH + c) * HW + n0 + l15;
                    #pragma unroll
                    for (int n = 0; n < 4; ++n) {
                        float base = gg[n][0] + ct1 * gg[n][1]
                                   + ct2 * gg[n][2] + ct3 * gg[n][3];
                        __builtin_nontemporal_store(
                            __expf(acc[m][n][r] + base), orow + n * 16);
                    }
                }
            }
        }
    }

#undef EPI
#undef ITER
}

extern "C" void kernel_launch(void* const* d_in, const int* in_sizes, int n_in,
                              void* d_out, int out_size, void* d_ws, size_t ws_size,
                              hipStream_t stream) {
    const float* theta_global = (const float*)d_in[0];  // [2,4,128,128]
    const float* theta_dir    = (const float*)d_in[1];  // [2,64,6,128,128]
    const float* t_vec        = (const float*)d_in[2];  // [630]
    const float* b_vec        = (const float*)d_in[3];  // [630]
    const float* P            = (const float*)d_in[4];  // [630,64]
    float* out = (float*)d_out;

    ushort* W2b = (ushort*)d_ws;    // 640*384*2 = 491,520 B

    (void)hipFuncSetAttribute((const void*)fused_gemm,
                              hipFuncAttributeMaxDynamicSharedMemorySize,
                              LDS_TOTAL);

    prep_kernel<<<dim3(MPAD), dim3(KDIR), 0, stream>>>(t_vec, b_vec, P, W2b);
    fused_gemm<<<dim3(HW / PANEL, BATCH), 256, LDS_TOTAL, stream>>>(
        W2b, theta_dir, t_vec, theta_global, out);
}

// Round 2
// 37.552 us; speedup vs baseline: 1.0636x; 1.0636x over previous
//
#include <hip/hip_runtime.h>
#include <math.h>

#define BATCH 2
#define NDIRS 64
#define NCH   630
#define MPAD  640
#define HW    16384         // 128*128
#define KDIR  384           // 64 dirs * 6 moments
#define NT    12            // k-steps of 32
#define PANEL 128           // px per block (512B HBM segments)
#define NPOSW 5             // m-positions (32 rows) per wave
#define NITER (NPOSW * NT)  // 60
#define BROWE 392           // Bs row stride in ushorts (784B)

// LDS layout (dynamic, 104960 B; 1 block/CU, 8 waves)
#define BS_OFF 0            // 128 * 392 * 2      = 100352
#define TV_OFF 100352       // 640 * 4            =   2560
#define TG_OFF 102912       // 4 * 128 * 4        =   2048
#define LDS_TOTAL 104960

typedef float f32x4 __attribute__((ext_vector_type(4)));
typedef short s16x8 __attribute__((ext_vector_type(8)));

__device__ __forceinline__ ushort f2bf(float f) {
    unsigned u = __builtin_bit_cast(unsigned, f);
    u = (u + 0x7FFFu + ((u >> 16) & 1u)) >> 16;   // RNE
    return (ushort)u;
}

__device__ __forceinline__ uint cvt_pk_bf16(float lo, float hi) {
    uint r;
    asm("v_cvt_pk_bf16_f32 %0, %1, %2" : "=v"(r) : "v"(lo), "v"(hi));
    return r;
}

// nontemporal 16B load: TD stream has ZERO intra-kernel reuse -> do not
// allocate in L2 (protects L2-resident W2b from eviction).
__device__ __forceinline__ f32x4 ntload(const float* p) {
    return __builtin_nontemporal_load((const f32x4*)p);
}

// ---------------------------------------------------------------------------
// K1: fold per-channel Taylor coefficients into projection matrix (bf16),
// k-slot-swizzled: within each 32-k step, 8-k slot s = k8 ^ ((c>>1)&3).
// Rows 630..639 zero.
// ---------------------------------------------------------------------------
__global__ void prep_kernel(const float* __restrict__ t_vec,
                            const float* __restrict__ b_vec,
                            const float* __restrict__ P,
                            ushort* __restrict__ W2b) {
    int c = blockIdx.x;          // 0..639
    int j = threadIdx.x;         // 0..383  (true k index)
    float w = 0.0f;
    if (c < NCH) {
        int d = j / 6, k = j - d * 6;
        float t = t_vec[c];
        float bb = b_vec[c];
        float coeff;
        switch (k) {
            case 0:  coeff = -bb;                           break;
            case 1:  coeff = t * bb;                        break;
            case 2:  coeff = 0.5f * bb * bb;                break;
            case 3:  coeff = -0.5f * t * t * bb;            break;
            case 4:  coeff = -0.5f * t * bb * bb;           break;
            default: coeff = -(1.0f / 6.0f) * bb * bb * bb; break;
        }
        w = coeff * P[c * NDIRS + d];
    }
    int kstep = j >> 5, k5 = j & 31, k8 = k5 >> 3, klo = k5 & 7;
    int s = k8 ^ ((c >> 1) & 3);
    W2b[c * KDIR + kstep * 32 + s * 8 + klo] = f2bf(w);
}

// ---------------------------------------------------------------------------
// K2: panel-resident fused GEMM, PANEL=128 (1 block/CU, 8 waves).
// Widening the panel 64->128 doubles every HBM segment (TD reads and out
// writes) from 256B to 512B at 64KB row stride -- attacks DRAM page-locality
// (avg achieved BW was ~3.3 TB/s vs 6.95 demonstrated by contiguous fill).
// Wave (mg,w): mg=row-group 0..3, w=px-half 0..1. Same per-thread work and
// wave occupancy (2/SIMD) as the PANEL=64 version. B-stage thread mapping
// kq2=mg*4+lhi, pg=w*16+l15 preserves the conflict-free 4x16 per-wave LDS
// write pattern; read-side swizzle invariant slot(row,k8)=k8^f3(row) is
// unchanged (row offsets w*64, n*16 are 0 mod 8).
// ---------------------------------------------------------------------------
__global__ __launch_bounds__(512, 2) void fused_gemm(
        const ushort* __restrict__ W2b,   // [MPAD][KDIR] bf16, slot-swizzled
        const float*  __restrict__ TD,    // [B][KDIR][HW] f32 (theta_dir)
        const float*  __restrict__ t_vec, // [NCH]
        const float*  __restrict__ TG,    // [B][4][HW]
        float* __restrict__ out)          // [B][NCH][HW]
{
    extern __shared__ char lds[];

    const int nt_ = blockIdx.x;           // 0..127 (128-px panel)
    const int bz  = blockIdx.y;           // 0..1
    const int n0  = nt_ * PANEL;

    const int tid  = threadIdx.x;         // 0..511
    const int lane = tid & 63;
    const int wv   = tid >> 6;            // 0..7
    const int mg   = wv & 3;              // A row group (c = mg*160 + ...)
    const int w    = wv >> 2;             // px half (0/1)
    const int l15 = lane & 15, lhi = lane >> 4;
    const int aslot = lhi ^ ((l15 >> 1) & 3);

    ushort* bsU = (ushort*)(lds + BS_OFF);
    float*  tvl = (float*)(lds + TV_OFF);
    float*  tgl = (float*)(lds + TG_OFF);

    // ---- stage t_vec -> LDS (OOB-safe, 512 threads cover 640 slots) ----
    tvl[tid] = t_vec[tid];
    if (tid < NCH - 512) tvl[tid + 512] = t_vec[tid + 512];
    else if (tid + 512 < MPAD) tvl[tid + 512] = 0.0f;
    // ---- stage TG (4 planes x 128 px) ----
    {
        int p = tid >> 7, px = tid & 127;
        tgl[p * PANEL + px] = TG[((size_t)bz * 4 + p) * HW + n0 + px];
    }

    // ---- A fragment base + first two iterations' fragments ----
    // Lane reads row (mg*160 + pi*32 + m*16 + l15), stored slot aslot:
    // row base multiple of 16 -> true k8 = lhi. Direct global->VGPR, no LDS.
    const ushort* aP = W2b + (mg * 160 + l15) * KDIR + aslot * 8;
    s16x8 afb[3][2];
    afb[0][0] = *(const s16x8*)(aP);                  // G=0: pi=0, ti=0
    afb[0][1] = *(const s16x8*)(aP + 16 * KDIR);
    afb[1][0] = *(const s16x8*)(aP + 32);             // G=1: pi=0, ti=1
    afb[1][1] = *(const s16x8*)(aP + 16 * KDIR + 32);
    __builtin_amdgcn_sched_barrier(0);

    // ---- stage B panel: 12 k-steps, depth-4 reg prefetch (NT loads) ----
    // kq2 = mg*4+lhi (0..15): krow pair {2kq2, 2kq2+1} within each 32-k step
    // pg  = w*16+l15  (0..31): px group pg*4 .. pg*4+3
    const int kq2 = mg * 4 + lhi;
    const int pg  = w * 16 + l15;
    const float* bR = TD + ((size_t)bz * KDIR + 2 * kq2) * HW + n0 + pg * 4;
    const int sxor = ((kq2 >> 2) ^ (pg & 3) ^ ((pg >> 2) & 3)) & 3;
    const int wbase = (kq2 & 3) * 2;      // uint pos within 8-ushort slot

    {
        f32x4 lo0, hi0, lo1, hi1, lo2, hi2, lo3, hi3;
        lo0 = ntload(bR);
        hi0 = ntload(bR + HW);
        lo1 = ntload(bR + (size_t)32 * HW);
        hi1 = ntload(bR + (size_t)33 * HW);
        lo2 = ntload(bR + (size_t)64 * HW);
        hi2 = ntload(bR + (size_t)65 * HW);

#define BSTEP(S, LC, HC, LN, HN)                                               \
        {                                                                      \
            if ((S) + 3 < NT) {                                                \
                LN = ntload(bR + (size_t)(((S) + 3) * 32) * HW);               \
                HN = ntload(bR + (size_t)(((S) + 3) * 32 + 1) * HW);           \
            }                                                                  \
            _Pragma("unroll")                                                  \
            for (int i = 0; i < 4; ++i) {                                      \
                uint w_ = cvt_pk_bf16(LC[i], HC[i]);                           \
                int s_ = (sxor ^ i) & 3;                                       \
                *(uint*)&bsU[(pg * 4 + i) * BROWE + (S) * 32 + s_ * 8 + wbase] = w_; \
            }                                                                  \
        }
        BSTEP(0, lo0, hi0, lo3, hi3)  BSTEP(1, lo1, hi1, lo0, hi0)
        BSTEP(2, lo2, hi2, lo1, hi1)  BSTEP(3, lo3, hi3, lo2, hi2)
        BSTEP(4, lo0, hi0, lo3, hi3)  BSTEP(5, lo1, hi1, lo0, hi0)
        BSTEP(6, lo2, hi2, lo1, hi1)  BSTEP(7, lo3, hi3, lo2, hi2)
        BSTEP(8, lo0, hi0, lo3, hi3)  BSTEP(9, lo1, hi1, lo0, hi0)
        BSTEP(10, lo2, hi2, lo1, hi1) BSTEP(11, lo3, hi3, lo2, hi2)
#undef BSTEP
    }

    // ---- single barrier: Bs/tv/tg visible ----
    asm volatile("s_waitcnt lgkmcnt(0)" ::: "memory");
    __builtin_amdgcn_s_barrier();
    __builtin_amdgcn_sched_barrier(0);

    // hoist TG values (wave covers its 64-px half: px = w*64 + n*16 + l15)
    float gg[4][4];
    #pragma unroll
    for (int n = 0; n < 4; ++n)
        #pragma unroll
        for (int p = 0; p < 4; ++p)
            gg[n][p] = tgl[p * PANEL + w * 64 + n * 16 + l15];

    f32x4 acc[2][4];
    #pragma unroll
    for (int m = 0; m < 2; ++m)
        #pragma unroll
        for (int n = 0; n < 4; ++n) acc[m][n] = (f32x4){0.f, 0.f, 0.f, 0.f};

    // ---- 60-iter pipeline; A prefetch 2 iters ahead into reg triple-buffer ----
#define ITER(G)                                                                \
    {                                                                          \
        constexpr int T_ = (G) % NT, buf_ = (G) % 3;                           \
        constexpr int gn_ = (G) + 2;                                           \
        if constexpr (gn_ < NITER) {                                           \
            constexpr int pi_ = gn_ / NT, ti_ = gn_ % NT, nb_ = gn_ % 3;       \
            afb[nb_][0] = *(const s16x8*)(aP + (pi_ * 32) * KDIR + ti_ * 32);  \
            afb[nb_][1] = *(const s16x8*)(aP + (pi_ * 32 + 16) * KDIR          \
                                          + ti_ * 32);                         \
            __builtin_amdgcn_sched_barrier(0);                                 \
        }                                                                      \
        s16x8 bf[4];                                                           \
        _Pragma("unroll")                                                      \
        for (int n = 0; n < 4; ++n) {                                          \
            const int rs_ = (lhi ^ (l15 & 3) ^ ((l15 >> 2) & 3) ^ (n)) & 3;    \
            bf[n] = *(const s16x8*)&bsU[(w * 64 + n * 16 + l15) * BROWE        \
                                        + T_ * 32 + rs_ * 8];                  \
        }                                                                      \
        __builtin_amdgcn_s_setprio(1);                                         \
        _Pragma("unroll")                                                      \
        for (int m = 0; m < 2; ++m)                                            \
            _Pragma("unroll")                                                  \
            for (int n = 0; n < 4; ++n)                                        \
                acc[m][n] = __builtin_amdgcn_mfma_f32_16x16x32_bf16(           \
                                afb[buf_][m], bf[n], acc[m][n], 0, 0, 0);      \
        __builtin_amdgcn_s_setprio(0);                                         \
    }

// EPI for positions 0..3: c = mg*160 + P*32 + ... <= 3*160+127 = 607 < 630,
// so stores are UNCONDITIONAL -> exactly 32 per thread.
#define EPI(P_)                                                                \
    {                                                                          \
        _Pragma("unroll")                                                      \
        for (int m = 0; m < 2; ++m) {                                          \
            _Pragma("unroll")                                                  \
            for (int r = 0; r < 4; ++r) {                                      \
                int c = mg * 160 + (P_) * 32 + m * 16 + lhi * 4 + r;           \
                float t_ = tvl[c];                                             \
                float ct1 = -t_, ct2 = 0.5f * t_ * t_;                         \
                float ct3 = -(1.0f / 6.0f) * t_ * t_ * t_;                     \
                float* orow = out + ((size_t)bz * NCH + c) * HW + n0           \
                              + w * 64 + l15;                                  \
                _Pragma("unroll")                                              \
                for (int n = 0; n < 4; ++n) {                                  \
                    float base = gg[n][0] + ct1 * gg[n][1]                     \
                               + ct2 * gg[n][2] + ct3 * gg[n][3];              \
                    __builtin_nontemporal_store(                               \
                        __expf(acc[m][n][r] + base), orow + n * 16);           \
                }                                                              \
            }                                                                  \
        }                                                                      \
        _Pragma("unroll")                                                      \
        for (int m = 0; m < 2; ++m)                                            \
            _Pragma("unroll")                                                  \
            for (int n = 0; n < 4; ++n) acc[m][n] = (f32x4){0.f,0.f,0.f,0.f};  \
    }

    ITER(0)  ITER(1)  ITER(2)  ITER(3)  ITER(4)  ITER(5)
    ITER(6)  ITER(7)  ITER(8)  ITER(9)  ITER(10) ITER(11)
    EPI(0)
    ITER(12) ITER(13) ITER(14) ITER(15) ITER(16) ITER(17)
    ITER(18) ITER(19) ITER(20) ITER(21) ITER(22) ITER(23)
    EPI(1)
    ITER(24) ITER(25) ITER(26) ITER(27) ITER(28) ITER(29)
    ITER(30) ITER(31) ITER(32) ITER(33) ITER(34) ITER(35)
    EPI(2)
    ITER(36) ITER(37) ITER(38) ITER(39) ITER(40) ITER(41)
    ITER(42) ITER(43) ITER(44) ITER(45) ITER(46) ITER(47)
    EPI(3)
    ITER(48) ITER(49) ITER(50) ITER(51) ITER(52) ITER(53)
    ITER(54) ITER(55) ITER(56) ITER(57) ITER(58) ITER(59)

    // ---- terminal EPI (position 4: rows 608..639 region, guarded) ----
    {
        #pragma unroll
        for (int m = 0; m < 2; ++m) {
            #pragma unroll
            for (int r = 0; r < 4; ++r) {
                int c = mg * 160 + 4 * 32 + m * 16 + lhi * 4 + r;
                if (c < NCH) {
                    float t_ = tvl[c];
                    float ct1 = -t_, ct2 = 0.5f * t_ * t_;
                    float ct3 = -(1.0f / 6.0f) * t_ * t_ * t_;
                    float* orow = out + ((size_t)bz * NCH + c) * HW + n0
                                  + w * 64 + l15;
                    #pragma unroll
                    for (int n = 0; n < 4; ++n) {
                        float base = gg[n][0] + ct1 * gg[n][1]
                                   + ct2 * gg[n][2] + ct3 * gg[n][3];
                        __builtin_nontemporal_store(
                            __expf(acc[m][n][r] + base), orow + n * 16);
                    }
                }
            }
        }
    }

#undef EPI
#undef ITER
}

extern "C" void kernel_launch(void* const* d_in, const int* in_sizes, int n_in,
                              void* d_out, int out_size, void* d_ws, size_t ws_size,
                              hipStream_t stream) {
    const float* theta_global = (const float*)d_in[0];  // [2,4,128,128]
    const float* theta_dir    = (const float*)d_in[1];  // [2,64,6,128,128]
    const float* t_vec        = (const float*)d_in[2];  // [630]
    const float* b_vec        = (const float*)d_in[3];  // [630]
    const float* P            = (const float*)d_in[4];  // [630,64]
    float* out = (float*)d_out;

    ushort* W2b = (ushort*)d_ws;    // 640*384*2 = 491,520 B

    (void)hipFuncSetAttribute((const void*)fused_gemm,
                              hipFuncAttributeMaxDynamicSharedMemorySize,
                              LDS_TOTAL);

    prep_kernel<<<dim3(MPAD), dim3(KDIR), 0, stream>>>(t_vec, b_vec, P, W2b);
    fused_gemm<<<dim3(HW / PANEL, BATCH), 512, LDS_TOTAL, stream>>>(
        W2b, theta_dir, t_vec, theta_global, out);
}